// Round 2
// baseline (503.049 us; speedup 1.0000x reference)
//
#include <hip/hip_runtime.h>
#include <hip/hip_fp16.h>

#define NTOT 8192
#define NHALF 4096
#define DIM 256
#define LOG2E 1.4426950408889634f
#define NEG_BIG -1e30f
#define COLSPLIT 16
#define BM 128
#define BN 64
#define CPB (NTOT / COLSPLIT) /* 512 cols per block */
#define NTILES (CPB / BN)     /* 8 */

typedef _Float16 half8 __attribute__((ext_vector_type(8)));
typedef float floatx4 __attribute__((ext_vector_type(4)));

// ------------- fused prep: normalize z1|z2 -> fp16 zn, target sims, zero out -------------
// block handles 2 pairs (i, i+N); wave w: {z1 p0, z2 p0, z1 p1, z2 p1}
__global__ __launch_bounds__(256) void k_prep(const float* __restrict__ z1,
                                              const float* __restrict__ z2,
                                              __half* __restrict__ zn,
                                              float* __restrict__ tsim,
                                              float* __restrict__ out) {
  __shared__ float sh[4][256];
  int w = threadIdx.x >> 6, lane = threadIdx.x & 63;
  int p = blockIdx.x * 2 + (w >> 1);
  int isZ2 = w & 1;
  const float* src = (isZ2 ? z2 : z1) + (size_t)p * DIM;
  float4 v = ((const float4*)src)[lane];
  float ss = v.x * v.x + v.y * v.y + v.z * v.z + v.w * v.w;
#pragma unroll
  for (int m = 1; m < 64; m <<= 1) ss += __shfl_xor(ss, m);
  float inv = 1.0f / fmaxf(sqrtf(ss), 1e-8f);
  __half h0 = __float2half_rn(v.x * inv), h1 = __float2half_rn(v.y * inv);
  __half h2 = __float2half_rn(v.z * inv), h3 = __float2half_rn(v.w * inv);
  int row = p + isZ2 * NHALF;
  __half2 a2, b2;
  a2.x = h0; a2.y = h1; b2.x = h2; b2.y = h3;
  __half2* dst = (__half2*)(zn + (size_t)row * DIM + lane * 4);
  dst[0] = a2;
  dst[1] = b2;
  float* s = sh[w];
  s[lane * 4 + 0] = __half2float(h0);
  s[lane * 4 + 1] = __half2float(h1);
  s[lane * 4 + 2] = __half2float(h2);
  s[lane * 4 + 3] = __half2float(h3);
  __syncthreads();
  if (w < 2) {  // wave w computes tsim for pair blockIdx*2 + w (fp16-rounded dot, fp32 acc)
    const float* sa = sh[w * 2];
    const float* sb = sh[w * 2 + 1];
    float4 xa = ((const float4*)sa)[lane];
    float4 xb = ((const float4*)sb)[lane];
    float d = xa.x * xb.x + xa.y * xb.y + xa.z * xb.z + xa.w * xb.w;
#pragma unroll
    for (int m = 1; m < 64; m <<= 1) d += __shfl_xor(d, m);
    if (lane == 0) {
      int pp = blockIdx.x * 2 + w;
      tsim[pp] = d;
      tsim[pp + NHALF] = d;
    }
  }
  if (blockIdx.x == 0 && threadIdx.x < 2) out[threadIdx.x] = 0.0f;
}

// ------------- per-tile epilogue: bounded-max exp-sum + argmax -------------
template <bool DIAG>
__device__ __forceinline__ void upd(const floatx4 (&acc)[2][4], int t, int colT, int cl,
                                    int quad, int wRow0, float kk, float* L, float* BV,
                                    int* BI) {
#pragma unroll
  for (int rt = 0; rt < 2; rt++) {
    int growB = wRow0 + rt * 16 + quad * 4;
#pragma unroll
    for (int r = 0; r < 4; r++) {
      int grow = growB + r;
      float v0 = acc[rt][0][r], v1 = acc[rt][1][r];
      float v2 = acc[rt][2][r], v3 = acc[rt][3][r];
      if (DIAG) {
        int c0 = colT + cl;
        if (c0 == grow) v0 = NEG_BIG;
        if (c0 + 16 == grow) v1 = NEG_BIG;
        if (c0 + 32 == grow) v2 = NEG_BIG;
        if (c0 + 48 == grow) v3 = NEG_BIG;
      }
      int slot = rt * 4 + r;
      // e = exp2(v*kk - kk)  (fixed softmax max at sim=1; sims bounded by 1)
      float e0 = __builtin_exp2f(__builtin_fmaf(v0, kk, -kk));
      float e1 = __builtin_exp2f(__builtin_fmaf(v1, kk, -kk));
      float e2 = __builtin_exp2f(__builtin_fmaf(v2, kk, -kk));
      float e3 = __builtin_exp2f(__builtin_fmaf(v3, kk, -kk));
      L[slot] += (e0 + e1) + (e2 + e3);
      // argmax over the 4 candidates (first-occurrence-wins tie semantics)
      float m01 = fmaxf(v0, v1);
      int i01 = (v1 > v0) ? 1 : 0;
      float m23 = fmaxf(v2, v3);
      int i23 = (v3 > v2) ? 3 : 2;
      float mm = fmaxf(m01, m23);
      int ii = (m23 > m01) ? i23 : i01;
      if (mm > BV[slot]) {
        BV[slot] = mm;
        BI[slot] = t * 4 + ii;  // 6-bit local index: tile(3b) x nt(2b)
      }
    }
  }
}

// ------------- main fused S-pass -------------
// grid = 64 rowTiles x 16 colSplits = 1024 blocks, 256 threads (4 waves x 32 rows)
__global__ __launch_bounds__(256, 4) void k_main(const __half* __restrict__ zn,
                                                 const float* __restrict__ logT,
                                                 float* __restrict__ pL,
                                                 float* __restrict__ pV,
                                                 int* __restrict__ pI) {
  __shared__ uint4 lds[BN * 32];  // 64 rows x 32 x 16B = 32 KB, xor-swizzled

  int bx = blockIdx.x;
  int rowTile = bx >> 4;
  int colq = bx & 15;
  int rowBase = rowTile * BM;
  int colBase = colq * CPB;
  int tid = threadIdx.x;
  int w = tid >> 6;
  int lane = tid & 63;
  int quad = lane >> 4;
  int cl = lane & 15;

  float invT = expf(-logT[0]);
  float kk = invT * LOG2E;

  // A fragments in registers: wave owns rows [rowBase+w*32, +32)
  half8 a[2][8];
  int wRow0 = rowBase + w * 32;
  {
    int ar0 = wRow0 + cl;
#pragma unroll
    for (int ks = 0; ks < 8; ks++) {
      a[0][ks] = *(const half8*)(zn + (size_t)ar0 * DIM + ks * 32 + quad * 8);
      a[1][ks] = *(const half8*)(zn + (size_t)(ar0 + 16) * DIM + ks * 32 + quad * 8);
    }
  }

  float L[8], BV[8];
  int BI[8];
#pragma unroll
  for (int s = 0; s < 8; s++) {
    L[s] = 0.f;
    BV[s] = -3e38f;
    BI[s] = 0;
  }

  for (int t = 0; t < NTILES; t++) {
    int colT = colBase + t * BN;
    __syncthreads();
    // stage B tile via global_load_lds (DMA writes base + lane*16; xor swizzle is
    // folded into each lane's GLOBAL chunk index so reads stay conflict-free)
#pragma unroll
    for (int i = 0; i < 8; i++) {
      int cbase = w * 16 + i * 2;
      int c = cbase + (lane >> 5);
      int ch = (lane & 31) ^ (c & 7);
      const void* gp = (const void*)(zn + (size_t)(colT + c) * DIM + ch * 8);
      __builtin_amdgcn_global_load_lds(
          (const __attribute__((address_space(1))) void*)gp,
          (__attribute__((address_space(3))) void*)&lds[cbase * 32], 16, 0, 0);
    }
    __syncthreads();

    floatx4 acc[2][4];
#pragma unroll
    for (int rt = 0; rt < 2; rt++)
#pragma unroll
      for (int nt = 0; nt < 4; nt++) acc[rt][nt] = (floatx4){0.f, 0.f, 0.f, 0.f};

#pragma unroll
    for (int nt = 0; nt < 4; nt++) {
      int bc = nt * 16 + cl;
#pragma unroll
      for (int ks = 0; ks < 8; ks++) {
        int ch = ks * 4 + quad;
        half8 b = *(const half8*)&lds[bc * 32 + (ch ^ (bc & 7))];
        acc[0][nt] = __builtin_amdgcn_mfma_f32_16x16x32_f16(a[0][ks], b, acc[0][nt], 0, 0, 0);
        acc[1][nt] = __builtin_amdgcn_mfma_f32_16x16x32_f16(a[1][ks], b, acc[1][nt], 0, 0, 0);
      }
    }

    // diagonal can only appear when this 64-col tile overlaps the wave's 32 rows
    bool hasDiag = (colT <= wRow0 + 31) && (colT + BN - 1 >= wRow0);
    if (hasDiag)
      upd<true>(acc, t, colT, cl, quad, wRow0, kk, L, BV, BI);
    else
      upd<false>(acc, t, colT, cl, quad, wRow0, kk, L, BV, BI);
  }

  // combine the 16 per-lane partials within each quad (plain sum for L; max+idx for argmax)
#pragma unroll
  for (int s = 0; s < 8; s++) {
    float l = L[s];
    float bv = BV[s];
    int bi6 = BI[s];
    int idx = ((bi6 >> 2) << 6) + ((bi6 & 3) << 4) + cl;  // col within this colsplit
#pragma unroll
    for (int sh = 1; sh < 16; sh <<= 1) {
      l += __shfl_xor(l, sh);
      float ov = __shfl_xor(bv, sh);
      int oi = __shfl_xor(idx, sh);
      if (ov > bv || (ov == bv && oi < idx)) {
        bv = ov;
        idx = oi;
      }
    }
    L[s] = l;
    BV[s] = bv;
    BI[s] = colBase + idx;
  }

  if (cl == 0) {
#pragma unroll
    for (int rt = 0; rt < 2; rt++)
#pragma unroll
      for (int r = 0; r < 4; r++) {
        int grow = wRow0 + rt * 16 + quad * 4 + r;
        int s = rt * 4 + r;
        int p = grow * COLSPLIT + colq;
        pL[p] = L[s];
        pV[p] = BV[s];
        pI[p] = BI[s];
      }
  }
}

// ------------- final reduce: combine col-splits, loss + correct -------------
__global__ __launch_bounds__(256) void k_reduce(const float* __restrict__ pL,
                                                const float* __restrict__ pV,
                                                const int* __restrict__ pI,
                                                const float* __restrict__ tsim,
                                                const float* __restrict__ logT,
                                                float* __restrict__ out) {
  int row = blockIdx.x * 256 + threadIdx.x;  // grid 32 -> 8192 rows
  float invT = expf(-logT[0]);
  float Lt = 0.f;
  float bv = -3e38f;
  int bi = -1;
#pragma unroll
  for (int q = 0; q < COLSPLIT; q++) {
    Lt += pL[row * COLSPLIT + q];
    float v = pV[row * COLSPLIT + q];
    if (v > bv) {  // ascending q => first occurrence wins
      bv = v;
      bi = pI[row * COLSPLIT + q];
    }
  }
  int tgt = (row < NHALF) ? row + NHALF : row - NHALF;
  // logZ = invT + log(Lt)  (fixed max at sim=1); loss_row = logZ - tsim*invT
  float loss = invT + logf(Lt) - tsim[row] * invT;
  float corr = (bi == tgt) ? 1.f : 0.f;

  __shared__ float sl[256], sc[256];
  sl[threadIdx.x] = loss;
  sc[threadIdx.x] = corr;
  __syncthreads();
  for (int s = 128; s > 0; s >>= 1) {
    if (threadIdx.x < s) {
      sl[threadIdx.x] += sl[threadIdx.x + s];
      sc[threadIdx.x] += sc[threadIdx.x + s];
    }
    __syncthreads();
  }
  if (threadIdx.x == 0) {
    atomicAdd(out + 0, sl[0] * (1.0f / (float)NTOT));
    atomicAdd(out + 1, sc[0] * 0.5f);
  }
}

extern "C" void kernel_launch(void* const* d_in, const int* in_sizes, int n_in,
                              void* d_out, int out_size, void* d_ws, size_t ws_size,
                              hipStream_t stream) {
  const float* z1 = (const float*)d_in[0];
  const float* z2 = (const float*)d_in[1];
  const float* logT = (const float*)d_in[2];
  float* out = (float*)d_out;

  char* ws = (char*)d_ws;
  __half* zn = (__half*)ws;                                // 4 MB
  float* tsim = (float*)(ws + 4 * 1024 * 1024);            // 32 KB
  float* pL = (float*)(ws + 4 * 1024 * 1024 + 32 * 1024);  // 512 KB
  float* pV = (float*)((char*)pL + NTOT * COLSPLIT * 4);   // 512 KB
  int* pI = (int*)((char*)pV + NTOT * COLSPLIT * 4);       // 512 KB

  k_prep<<<NHALF / 2, 256, 0, stream>>>(z1, z2, zn, tsim, out);
  k_main<<<(NTOT / BM) * COLSPLIT, 256, 0, stream>>>(zn, logT, pL, pV, pI);
  k_reduce<<<NTOT / 256, 256, 0, stream>>>(pL, pV, pI, tsim, logT, out);
}

// Round 3
// 455.285 us; speedup vs baseline: 1.1049x; 1.1049x over previous
//
#include <hip/hip_runtime.h>
#include <hip/hip_fp16.h>

#define NTOT 8192
#define NHALF 4096
#define DIM 256
#define LOG2E 1.4426950408889634f
#define NEG_BIG -1e30f
#define COLSPLIT 16
#define BM 128
#define BN 64
#define CPB (NTOT / COLSPLIT) /* 512 cols per block */
#define NTILES (CPB / BN)     /* 8 */
#define NROWTILE (NTOT / BM)  /* 64 */

typedef _Float16 half8 __attribute__((ext_vector_type(8)));
typedef float floatx4 __attribute__((ext_vector_type(4)));

// ------------- fused prep: normalize z1|z2 -> fp16 zn, target sims, zero out+cnt -------------
__global__ __launch_bounds__(256) void k_prep(const float* __restrict__ z1,
                                              const float* __restrict__ z2,
                                              __half* __restrict__ zn,
                                              float* __restrict__ tsim,
                                              int* __restrict__ cnt,
                                              float* __restrict__ out) {
  __shared__ float sh[4][256];
  int w = threadIdx.x >> 6, lane = threadIdx.x & 63;
  int p = blockIdx.x * 2 + (w >> 1);
  int isZ2 = w & 1;
  const float* src = (isZ2 ? z2 : z1) + (size_t)p * DIM;
  float4 v = ((const float4*)src)[lane];
  float ss = v.x * v.x + v.y * v.y + v.z * v.z + v.w * v.w;
#pragma unroll
  for (int m = 1; m < 64; m <<= 1) ss += __shfl_xor(ss, m);
  float inv = 1.0f / fmaxf(sqrtf(ss), 1e-8f);
  __half h0 = __float2half_rn(v.x * inv), h1 = __float2half_rn(v.y * inv);
  __half h2 = __float2half_rn(v.z * inv), h3 = __float2half_rn(v.w * inv);
  int row = p + isZ2 * NHALF;
  __half2 a2, b2;
  a2.x = h0; a2.y = h1; b2.x = h2; b2.y = h3;
  __half2* dst = (__half2*)(zn + (size_t)row * DIM + lane * 4);
  dst[0] = a2;
  dst[1] = b2;
  float* s = sh[w];
  s[lane * 4 + 0] = __half2float(h0);
  s[lane * 4 + 1] = __half2float(h1);
  s[lane * 4 + 2] = __half2float(h2);
  s[lane * 4 + 3] = __half2float(h3);
  __syncthreads();
  if (w < 2) {  // wave w computes tsim for pair blockIdx*2 + w (fp16-rounded dot, fp32 acc)
    const float* sa = sh[w * 2];
    const float* sb = sh[w * 2 + 1];
    float4 xa = ((const float4*)sa)[lane];
    float4 xb = ((const float4*)sb)[lane];
    float d = xa.x * xb.x + xa.y * xb.y + xa.z * xb.z + xa.w * xb.w;
#pragma unroll
    for (int m = 1; m < 64; m <<= 1) d += __shfl_xor(d, m);
    if (lane == 0) {
      int pp = blockIdx.x * 2 + w;
      tsim[pp] = d;
      tsim[pp + NHALF] = d;
    }
  }
  if (blockIdx.x == 0) {
    if (threadIdx.x < 2) out[threadIdx.x] = 0.0f;
    if (threadIdx.x < NROWTILE) cnt[threadIdx.x] = 0;
  }
}

// ------------- per-tile epilogue: bounded-max exp-sum + argmax -------------
template <bool DIAG>
__device__ __forceinline__ void upd(const floatx4 (&acc)[2][4], int t, int colT, int cl,
                                    int quad, int wRow0, float kk, float* L, float* BV,
                                    int* BI) {
#pragma unroll
  for (int rt = 0; rt < 2; rt++) {
    int growB = wRow0 + rt * 16 + quad * 4;
#pragma unroll
    for (int r = 0; r < 4; r++) {
      int grow = growB + r;
      float v0 = acc[rt][0][r], v1 = acc[rt][1][r];
      float v2 = acc[rt][2][r], v3 = acc[rt][3][r];
      if (DIAG) {
        int c0 = colT + cl;
        if (c0 == grow) v0 = NEG_BIG;
        if (c0 + 16 == grow) v1 = NEG_BIG;
        if (c0 + 32 == grow) v2 = NEG_BIG;
        if (c0 + 48 == grow) v3 = NEG_BIG;
      }
      int slot = rt * 4 + r;
      // e = exp2(v*kk - kk)  (fixed softmax max at sim=1; sims bounded by 1)
      float e0 = __builtin_exp2f(__builtin_fmaf(v0, kk, -kk));
      float e1 = __builtin_exp2f(__builtin_fmaf(v1, kk, -kk));
      float e2 = __builtin_exp2f(__builtin_fmaf(v2, kk, -kk));
      float e3 = __builtin_exp2f(__builtin_fmaf(v3, kk, -kk));
      L[slot] += (e0 + e1) + (e2 + e3);
      // argmax over the 4 candidates (first-occurrence-wins tie semantics)
      float m01 = fmaxf(v0, v1);
      int i01 = (v1 > v0) ? 1 : 0;
      float m23 = fmaxf(v2, v3);
      int i23 = (v3 > v2) ? 3 : 2;
      float mm = fmaxf(m01, m23);
      int ii = (m23 > m01) ? i23 : i01;
      if (mm > BV[slot]) {
        BV[slot] = mm;
        BI[slot] = t * 4 + ii;  // 5-bit local index: tile(3b) x nt(2b)
      }
    }
  }
}

// ------------- main fused S-pass + last-block reduction -------------
// grid = 64 rowTiles x 16 colSplits = 1024 blocks, 256 threads (4 waves x 32 rows)
// launch_bounds(256,3): VGPR budget 170 >= ~150 demand -> NO SPILL (the (256,4)
// variant capped at 128 and spilled 2.2 GB of scratch to HBM: 440 us)
__global__ __launch_bounds__(256, 3) void k_main(const __half* __restrict__ zn,
                                                 const float* __restrict__ logT,
                                                 float* __restrict__ pL,
                                                 float* __restrict__ pV,
                                                 int* __restrict__ pI,
                                                 const float* __restrict__ tsim,
                                                 int* __restrict__ cnt,
                                                 float* __restrict__ out) {
  __shared__ uint4 lds[BN * 32];  // 64 rows x 32 x 16B = 32 KB, xor-swizzled
  __shared__ int sLast;

  int bx = blockIdx.x;
  int rowTile = bx >> 4;
  int colq = bx & 15;
  int rowBase = rowTile * BM;
  int colBase = colq * CPB;
  int tid = threadIdx.x;
  int w = tid >> 6;
  int lane = tid & 63;
  int quad = lane >> 4;
  int cl = lane & 15;

  float invT = expf(-logT[0]);
  float kk = invT * LOG2E;

  // A fragments in registers: wave owns rows [rowBase+w*32, +32)
  half8 a[2][8];
  int wRow0 = rowBase + w * 32;
  {
    int ar0 = wRow0 + cl;
#pragma unroll
    for (int ks = 0; ks < 8; ks++) {
      a[0][ks] = *(const half8*)(zn + (size_t)ar0 * DIM + ks * 32 + quad * 8);
      a[1][ks] = *(const half8*)(zn + (size_t)(ar0 + 16) * DIM + ks * 32 + quad * 8);
    }
  }

  float L[8], BV[8];
  int BI[8];
#pragma unroll
  for (int s = 0; s < 8; s++) {
    L[s] = 0.f;
    BV[s] = -3e38f;
    BI[s] = 0;
  }

  for (int t = 0; t < NTILES; t++) {
    int colT = colBase + t * BN;
    __syncthreads();
    // stage B tile via global_load_lds (DMA writes base + lane*16; xor swizzle is
    // folded into each lane's GLOBAL chunk index so reads stay conflict-free)
#pragma unroll
    for (int i = 0; i < 8; i++) {
      int cbase = w * 16 + i * 2;
      int c = cbase + (lane >> 5);
      int ch = (lane & 31) ^ (c & 7);
      const void* gp = (const void*)(zn + (size_t)(colT + c) * DIM + ch * 8);
      __builtin_amdgcn_global_load_lds(
          (const __attribute__((address_space(1))) void*)gp,
          (__attribute__((address_space(3))) void*)&lds[cbase * 32], 16, 0, 0);
    }
    __syncthreads();

    floatx4 acc[2][4];
#pragma unroll
    for (int rt = 0; rt < 2; rt++)
#pragma unroll
      for (int nt = 0; nt < 4; nt++) acc[rt][nt] = (floatx4){0.f, 0.f, 0.f, 0.f};

#pragma unroll
    for (int nt = 0; nt < 4; nt++) {
      int bc = nt * 16 + cl;
#pragma unroll
      for (int ks = 0; ks < 8; ks++) {
        int ch = ks * 4 + quad;
        half8 b = *(const half8*)&lds[bc * 32 + (ch ^ (bc & 7))];
        acc[0][nt] = __builtin_amdgcn_mfma_f32_16x16x32_f16(a[0][ks], b, acc[0][nt], 0, 0, 0);
        acc[1][nt] = __builtin_amdgcn_mfma_f32_16x16x32_f16(a[1][ks], b, acc[1][nt], 0, 0, 0);
      }
    }

    // diagonal can only appear when this 64-col tile overlaps the wave's 32 rows
    bool hasDiag = (colT <= wRow0 + 31) && (colT + BN - 1 >= wRow0);
    if (hasDiag)
      upd<true>(acc, t, colT, cl, quad, wRow0, kk, L, BV, BI);
    else
      upd<false>(acc, t, colT, cl, quad, wRow0, kk, L, BV, BI);
  }

  // combine the 16 per-lane partials within each quad (plain sum for L; max+idx for argmax)
#pragma unroll
  for (int s = 0; s < 8; s++) {
    float l = L[s];
    float bv = BV[s];
    int bi6 = BI[s];
    int idx = ((bi6 >> 2) << 6) + ((bi6 & 3) << 4) + cl;  // col within this colsplit
#pragma unroll
    for (int sh = 1; sh < 16; sh <<= 1) {
      l += __shfl_xor(l, sh);
      float ov = __shfl_xor(bv, sh);
      int oi = __shfl_xor(idx, sh);
      if (ov > bv || (ov == bv && oi < idx)) {
        bv = ov;
        idx = oi;
      }
    }
    L[s] = l;
    BV[s] = bv;
    BI[s] = colBase + idx;
  }

  if (cl == 0) {
#pragma unroll
    for (int rt = 0; rt < 2; rt++)
#pragma unroll
      for (int r = 0; r < 4; r++) {
        int grow = wRow0 + rt * 16 + quad * 4 + r;
        int s = rt * 4 + r;
        int p = grow * COLSPLIT + colq;
        pL[p] = L[s];
        pV[p] = BV[s];
        pI[p] = BI[s];
      }
  }

  // ---- split-K style completion: last col-split block of this rowTile reduces ----
  __threadfence();  // release partial writes to device scope
  __syncthreads();
  if (tid == 0) {
    int old = atomicAdd(&cnt[rowTile], 1);
    sLast = (old == COLSPLIT - 1) ? 1 : 0;
  }
  __syncthreads();
  if (!sLast) return;
  __threadfence();  // acquire: invalidate stale cached lines before reading partials

  float loss = 0.f, corr = 0.f;
  if (tid < BM) {
    int row = rowBase + tid;
    float Lt = 0.f;
    float bv = -3e38f;
    int bi = -1;
#pragma unroll
    for (int q = 0; q < COLSPLIT; q++) {
      Lt += pL[row * COLSPLIT + q];
      float v = pV[row * COLSPLIT + q];
      if (v > bv) {  // ascending q => first occurrence wins
        bv = v;
        bi = pI[row * COLSPLIT + q];
      }
    }
    int tgt = (row < NHALF) ? row + NHALF : row - NHALF;
    // logZ = invT + log(Lt) (fixed max at sim=1); loss_row = logZ - tsim*invT
    loss = invT + logf(Lt) - tsim[row] * invT;
    corr = (bi == tgt) ? 1.f : 0.f;
  }
  float* sl = (float*)lds;        // reuse LDS (safe after syncthreads)
  float* sc = (float*)lds + 256;
  sl[tid] = loss;
  sc[tid] = corr;
  __syncthreads();
  for (int s = 128; s > 0; s >>= 1) {
    if (tid < s) {
      sl[tid] += sl[tid + s];
      sc[tid] += sc[tid + s];
    }
    __syncthreads();
  }
  if (tid == 0) {
    atomicAdd(out + 0, sl[0] * (1.0f / (float)NTOT));
    atomicAdd(out + 1, sc[0] * 0.5f);
  }
}

extern "C" void kernel_launch(void* const* d_in, const int* in_sizes, int n_in,
                              void* d_out, int out_size, void* d_ws, size_t ws_size,
                              hipStream_t stream) {
  const float* z1 = (const float*)d_in[0];
  const float* z2 = (const float*)d_in[1];
  const float* logT = (const float*)d_in[2];
  float* out = (float*)d_out;

  char* ws = (char*)d_ws;
  __half* zn = (__half*)ws;                                 // 4 MB
  float* tsim = (float*)(ws + 4 * 1024 * 1024);             // 32 KB
  float* pL = (float*)(ws + 4 * 1024 * 1024 + 32 * 1024);   // 512 KB
  float* pV = (float*)((char*)pL + NTOT * COLSPLIT * 4);    // 512 KB
  int* pI = (int*)((char*)pV + NTOT * COLSPLIT * 4);        // 512 KB
  int* cnt = (int*)((char*)pI + NTOT * COLSPLIT * 4);       // 256 B

  k_prep<<<NHALF / 2, 256, 0, stream>>>(z1, z2, zn, tsim, cnt, out);
  k_main<<<NROWTILE * COLSPLIT, 256, 0, stream>>>(zn, logT, pL, pV, pI, tsim, cnt, out);
}

// Round 4
// 261.784 us; speedup vs baseline: 1.9216x; 1.7392x over previous
//
#include <hip/hip_runtime.h>
#include <hip/hip_fp16.h>

#define NTOT 8192
#define NHALF 4096
#define DIM 256
#define LOG2E 1.4426950408889634f
#define NEG_BIG -1e30f
#define COLSPLIT 16
#define BM 128
#define BN 64
#define CPB (NTOT / COLSPLIT) /* 512 cols per block */
#define NTILES (CPB / BN)     /* 8 */
#define NROWTILE (NTOT / BM)  /* 64 */

typedef _Float16 half8 __attribute__((ext_vector_type(8)));
typedef float floatx4 __attribute__((ext_vector_type(4)));

// ------------- fused prep: normalize z1|z2 -> fp16 zn, target sims, zero out+cnt -------------
__global__ __launch_bounds__(256) void k_prep(const float* __restrict__ z1,
                                              const float* __restrict__ z2,
                                              __half* __restrict__ zn,
                                              float* __restrict__ tsim,
                                              int* __restrict__ cnt,
                                              float* __restrict__ out) {
  __shared__ float sh[4][256];
  int w = threadIdx.x >> 6, lane = threadIdx.x & 63;
  int p = blockIdx.x * 2 + (w >> 1);
  int isZ2 = w & 1;
  const float* src = (isZ2 ? z2 : z1) + (size_t)p * DIM;
  float4 v = ((const float4*)src)[lane];
  float ss = v.x * v.x + v.y * v.y + v.z * v.z + v.w * v.w;
#pragma unroll
  for (int m = 1; m < 64; m <<= 1) ss += __shfl_xor(ss, m);
  float inv = 1.0f / fmaxf(sqrtf(ss), 1e-8f);
  __half h0 = __float2half_rn(v.x * inv), h1 = __float2half_rn(v.y * inv);
  __half h2 = __float2half_rn(v.z * inv), h3 = __float2half_rn(v.w * inv);
  int row = p + isZ2 * NHALF;
  __half2 a2, b2;
  a2.x = h0; a2.y = h1; b2.x = h2; b2.y = h3;
  __half2* dst = (__half2*)(zn + (size_t)row * DIM + lane * 4);
  dst[0] = a2;
  dst[1] = b2;
  float* s = sh[w];
  s[lane * 4 + 0] = __half2float(h0);
  s[lane * 4 + 1] = __half2float(h1);
  s[lane * 4 + 2] = __half2float(h2);
  s[lane * 4 + 3] = __half2float(h3);
  __syncthreads();
  if (w < 2) {  // wave w computes tsim for pair blockIdx*2 + w (fp16-rounded dot, fp32 acc)
    const float* sa = sh[w * 2];
    const float* sb = sh[w * 2 + 1];
    float4 xa = ((const float4*)sa)[lane];
    float4 xb = ((const float4*)sb)[lane];
    float d = xa.x * xb.x + xa.y * xb.y + xa.z * xb.z + xa.w * xb.w;
#pragma unroll
    for (int m = 1; m < 64; m <<= 1) d += __shfl_xor(d, m);
    if (lane == 0) {
      int pp = blockIdx.x * 2 + w;
      tsim[pp] = d;
      tsim[pp + NHALF] = d;
    }
  }
  if (blockIdx.x == 0) {
    if (threadIdx.x < 2) out[threadIdx.x] = 0.0f;
    if (threadIdx.x < NROWTILE) cnt[threadIdx.x] = 0;
  }
}

// ------------- per-tile epilogue: bounded-max exp-sum + argmax -------------
template <bool DIAG>
__device__ __forceinline__ void upd(const floatx4 (&acc)[2][4], int t, int colT, int cl,
                                    int quad, int wRow0, float kk, float* L, float* BV,
                                    int* BI) {
#pragma unroll
  for (int rt = 0; rt < 2; rt++) {
    int growB = wRow0 + rt * 16 + quad * 4;
#pragma unroll
    for (int r = 0; r < 4; r++) {
      int grow = growB + r;
      float v0 = acc[rt][0][r], v1 = acc[rt][1][r];
      float v2 = acc[rt][2][r], v3 = acc[rt][3][r];
      if (DIAG) {
        int c0 = colT + cl;
        if (c0 == grow) v0 = NEG_BIG;
        if (c0 + 16 == grow) v1 = NEG_BIG;
        if (c0 + 32 == grow) v2 = NEG_BIG;
        if (c0 + 48 == grow) v3 = NEG_BIG;
      }
      int slot = rt * 4 + r;
      // e = exp2(v*kk - kk)  (fixed softmax max at sim=1; sims bounded by 1)
      float e0 = __builtin_exp2f(__builtin_fmaf(v0, kk, -kk));
      float e1 = __builtin_exp2f(__builtin_fmaf(v1, kk, -kk));
      float e2 = __builtin_exp2f(__builtin_fmaf(v2, kk, -kk));
      float e3 = __builtin_exp2f(__builtin_fmaf(v3, kk, -kk));
      L[slot] += (e0 + e1) + (e2 + e3);
      // argmax over the 4 candidates (first-occurrence-wins tie semantics)
      float m01 = fmaxf(v0, v1);
      int i01 = (v1 > v0) ? 1 : 0;
      float m23 = fmaxf(v2, v3);
      int i23 = (v3 > v2) ? 3 : 2;
      float mm = fmaxf(m01, m23);
      int ii = (m23 > m01) ? i23 : i01;
      if (mm > BV[slot]) {
        BV[slot] = mm;
        BI[slot] = t * 4 + ii;  // 5-bit local index: tile(3b) x nt(2b)
      }
    }
  }
}

// ------------- main fused S-pass + last-block reduction -------------
// grid = 64 rowTiles x 16 colSplits = 1024 blocks, 256 threads (4 waves x 32 rows)
// launch_bounds(256,2): VGPR budget 256 >= ~140 demand. (256,3)=170 and (256,4)=128
// both made the compiler pick a bad arch/agpr split and SPILL (84 resp 64 arch
// VGPRs, 0.6-2.2 GB scratch HBM traffic, 6x slowdown). Do not tighten this.
__global__ __launch_bounds__(256, 2) void k_main(const __half* __restrict__ zn,
                                                 const float* __restrict__ logT,
                                                 float* __restrict__ pL,
                                                 float* __restrict__ pV,
                                                 int* __restrict__ pI,
                                                 const float* __restrict__ tsim,
                                                 int* __restrict__ cnt,
                                                 float* __restrict__ out) {
  __shared__ uint4 lds[BN * 32];  // 64 rows x 32 x 16B = 32 KB, xor-swizzled
  __shared__ int sLast;

  int bx = blockIdx.x;
  int rowTile = bx >> 4;
  int colq = bx & 15;
  int rowBase = rowTile * BM;
  int colBase = colq * CPB;
  int tid = threadIdx.x;
  int w = tid >> 6;
  int lane = tid & 63;
  int quad = lane >> 4;
  int cl = lane & 15;

  float invT = expf(-logT[0]);
  float kk = invT * LOG2E;

  // A fragments in registers: wave owns rows [rowBase+w*32, +32)
  half8 a[2][8];
  int wRow0 = rowBase + w * 32;
  {
    int ar0 = wRow0 + cl;
#pragma unroll
    for (int ks = 0; ks < 8; ks++) {
      a[0][ks] = *(const half8*)(zn + (size_t)ar0 * DIM + ks * 32 + quad * 8);
      a[1][ks] = *(const half8*)(zn + (size_t)(ar0 + 16) * DIM + ks * 32 + quad * 8);
    }
  }

  float L[8], BV[8];
  int BI[8];
#pragma unroll
  for (int s = 0; s < 8; s++) {
    L[s] = 0.f;
    BV[s] = -3e38f;
    BI[s] = 0;
  }

  for (int t = 0; t < NTILES; t++) {
    int colT = colBase + t * BN;
    __syncthreads();
    // stage B tile via global_load_lds (DMA writes base + lane*16; xor swizzle is
    // folded into each lane's GLOBAL chunk index so reads stay conflict-free)
#pragma unroll
    for (int i = 0; i < 8; i++) {
      int cbase = w * 16 + i * 2;
      int c = cbase + (lane >> 5);
      int ch = (lane & 31) ^ (c & 7);
      const void* gp = (const void*)(zn + (size_t)(colT + c) * DIM + ch * 8);
      __builtin_amdgcn_global_load_lds(
          (const __attribute__((address_space(1))) void*)gp,
          (__attribute__((address_space(3))) void*)&lds[cbase * 32], 16, 0, 0);
    }
    __syncthreads();

    floatx4 acc[2][4];
#pragma unroll
    for (int rt = 0; rt < 2; rt++)
#pragma unroll
      for (int nt = 0; nt < 4; nt++) acc[rt][nt] = (floatx4){0.f, 0.f, 0.f, 0.f};

#pragma unroll
    for (int nt = 0; nt < 4; nt++) {
      int bc = nt * 16 + cl;
#pragma unroll
      for (int ks = 0; ks < 8; ks++) {
        int ch = ks * 4 + quad;
        half8 b = *(const half8*)&lds[bc * 32 + (ch ^ (bc & 7))];
        acc[0][nt] = __builtin_amdgcn_mfma_f32_16x16x32_f16(a[0][ks], b, acc[0][nt], 0, 0, 0);
        acc[1][nt] = __builtin_amdgcn_mfma_f32_16x16x32_f16(a[1][ks], b, acc[1][nt], 0, 0, 0);
      }
    }

    // diagonal can only appear when this 64-col tile overlaps the wave's 32 rows
    bool hasDiag = (colT <= wRow0 + 31) && (colT + BN - 1 >= wRow0);
    if (hasDiag)
      upd<true>(acc, t, colT, cl, quad, wRow0, kk, L, BV, BI);
    else
      upd<false>(acc, t, colT, cl, quad, wRow0, kk, L, BV, BI);
  }

  // combine the 16 per-lane partials within each quad (plain sum for L; max+idx for argmax)
#pragma unroll
  for (int s = 0; s < 8; s++) {
    float l = L[s];
    float bv = BV[s];
    int bi6 = BI[s];
    int idx = ((bi6 >> 2) << 6) + ((bi6 & 3) << 4) + cl;  // col within this colsplit
#pragma unroll
    for (int sh = 1; sh < 16; sh <<= 1) {
      l += __shfl_xor(l, sh);
      float ov = __shfl_xor(bv, sh);
      int oi = __shfl_xor(idx, sh);
      if (ov > bv || (ov == bv && oi < idx)) {
        bv = ov;
        idx = oi;
      }
    }
    L[s] = l;
    BV[s] = bv;
    BI[s] = colBase + idx;
  }

  if (cl == 0) {
#pragma unroll
    for (int rt = 0; rt < 2; rt++)
#pragma unroll
      for (int r = 0; r < 4; r++) {
        int grow = wRow0 + rt * 16 + quad * 4 + r;
        int s = rt * 4 + r;
        int p = grow * COLSPLIT + colq;
        pL[p] = L[s];
        pV[p] = BV[s];
        pI[p] = BI[s];
      }
  }

  // ---- split-K style completion: last col-split block of this rowTile reduces ----
  __threadfence();  // release partial writes to device scope
  __syncthreads();
  if (tid == 0) {
    int old = atomicAdd(&cnt[rowTile], 1);
    sLast = (old == COLSPLIT - 1) ? 1 : 0;
  }
  __syncthreads();
  if (!sLast) return;
  __threadfence();  // acquire: invalidate stale cached lines before reading partials

  float loss = 0.f, corr = 0.f;
  if (tid < BM) {
    int row = rowBase + tid;
    float Lt = 0.f;
    float bv = -3e38f;
    int bi = -1;
#pragma unroll
    for (int q = 0; q < COLSPLIT; q++) {
      Lt += pL[row * COLSPLIT + q];
      float v = pV[row * COLSPLIT + q];
      if (v > bv) {  // ascending q => first occurrence wins
        bv = v;
        bi = pI[row * COLSPLIT + q];
      }
    }
    int tgt = (row < NHALF) ? row + NHALF : row - NHALF;
    // logZ = invT + log(Lt) (fixed max at sim=1); loss_row = logZ - tsim*invT
    loss = invT + logf(Lt) - tsim[row] * invT;
    corr = (bi == tgt) ? 1.f : 0.f;
  }
  float* sl = (float*)lds;        // reuse LDS (safe after syncthreads)
  float* sc = (float*)lds + 256;
  sl[tid] = loss;
  sc[tid] = corr;
  __syncthreads();
  for (int s = 128; s > 0; s >>= 1) {
    if (tid < s) {
      sl[tid] += sl[tid + s];
      sc[tid] += sc[tid + s];
    }
    __syncthreads();
  }
  if (tid == 0) {
    atomicAdd(out + 0, sl[0] * (1.0f / (float)NTOT));
    atomicAdd(out + 1, sc[0] * 0.5f);
  }
}

extern "C" void kernel_launch(void* const* d_in, const int* in_sizes, int n_in,
                              void* d_out, int out_size, void* d_ws, size_t ws_size,
                              hipStream_t stream) {
  const float* z1 = (const float*)d_in[0];
  const float* z2 = (const float*)d_in[1];
  const float* logT = (const float*)d_in[2];
  float* out = (float*)d_out;

  char* ws = (char*)d_ws;
  __half* zn = (__half*)ws;                                 // 4 MB
  float* tsim = (float*)(ws + 4 * 1024 * 1024);             // 32 KB
  float* pL = (float*)(ws + 4 * 1024 * 1024 + 32 * 1024);   // 512 KB
  float* pV = (float*)((char*)pL + NTOT * COLSPLIT * 4);    // 512 KB
  int* pI = (int*)((char*)pV + NTOT * COLSPLIT * 4);        // 512 KB
  int* cnt = (int*)((char*)pI + NTOT * COLSPLIT * 4);       // 256 B

  k_prep<<<NHALF / 2, 256, 0, stream>>>(z1, z2, zn, tsim, cnt, out);
  k_main<<<NROWTILE * COLSPLIT, 256, 0, stream>>>(zn, logT, pL, pV, pI, tsim, cnt, out);
}

// Round 5
// 183.825 us; speedup vs baseline: 2.7366x; 1.4241x over previous
//
#include <hip/hip_runtime.h>
#include <hip/hip_fp16.h>

#define NTOT 8192
#define NHALF 4096
#define DIM 256
#define LOG2E 1.4426950408889634f
#define NEG_BIG -1e30f
#define COLSPLIT 8
#define BM 128
#define BN 64
#define CPB (NTOT / COLSPLIT) /* 1024 cols per block */
#define NTILES (CPB / BN)     /* 16 */
#define NROWTILE (NTOT / BM)  /* 64 */

typedef _Float16 half8 __attribute__((ext_vector_type(8)));
typedef float floatx4 __attribute__((ext_vector_type(4)));

// ------------- fused prep: normalize z1|z2 -> fp16 zn, target sims, zero out+cnt -------------
__global__ __launch_bounds__(256) void k_prep(const float* __restrict__ z1,
                                              const float* __restrict__ z2,
                                              __half* __restrict__ zn,
                                              float* __restrict__ tsim,
                                              int* __restrict__ cnt,
                                              float* __restrict__ out) {
  __shared__ float sh[4][256];
  int w = threadIdx.x >> 6, lane = threadIdx.x & 63;
  int p = blockIdx.x * 2 + (w >> 1);
  int isZ2 = w & 1;
  const float* src = (isZ2 ? z2 : z1) + (size_t)p * DIM;
  float4 v = ((const float4*)src)[lane];
  float ss = v.x * v.x + v.y * v.y + v.z * v.z + v.w * v.w;
#pragma unroll
  for (int m = 1; m < 64; m <<= 1) ss += __shfl_xor(ss, m);
  float inv = 1.0f / fmaxf(sqrtf(ss), 1e-8f);
  __half h0 = __float2half_rn(v.x * inv), h1 = __float2half_rn(v.y * inv);
  __half h2 = __float2half_rn(v.z * inv), h3 = __float2half_rn(v.w * inv);
  int row = p + isZ2 * NHALF;
  __half2 a2, b2;
  a2.x = h0; a2.y = h1; b2.x = h2; b2.y = h3;
  __half2* dst = (__half2*)(zn + (size_t)row * DIM + lane * 4);
  dst[0] = a2;
  dst[1] = b2;
  float* s = sh[w];
  s[lane * 4 + 0] = __half2float(h0);
  s[lane * 4 + 1] = __half2float(h1);
  s[lane * 4 + 2] = __half2float(h2);
  s[lane * 4 + 3] = __half2float(h3);
  __syncthreads();
  if (w < 2) {  // wave w computes tsim for pair blockIdx*2 + w (fp16-rounded dot, fp32 acc)
    const float* sa = sh[w * 2];
    const float* sb = sh[w * 2 + 1];
    float4 xa = ((const float4*)sa)[lane];
    float4 xb = ((const float4*)sb)[lane];
    float d = xa.x * xb.x + xa.y * xb.y + xa.z * xb.z + xa.w * xb.w;
#pragma unroll
    for (int m = 1; m < 64; m <<= 1) d += __shfl_xor(d, m);
    if (lane == 0) {
      int pp = blockIdx.x * 2 + w;
      tsim[pp] = d;
      tsim[pp + NHALF] = d;
    }
  }
  if (blockIdx.x == 0) {
    if (threadIdx.x < 2) out[threadIdx.x] = 0.0f;
    if (threadIdx.x < NROWTILE) cnt[threadIdx.x] = 0;
  }
}

// ------------- per-tile epilogue: bounded-max exp-sum + argmax -------------
template <bool DIAG>
__device__ __forceinline__ void upd(const floatx4 (&acc)[2][4], int t, int colT, int cl,
                                    int quad, int wRow0, float kk, float* L, float* BV,
                                    int* BI) {
#pragma unroll
  for (int rt = 0; rt < 2; rt++) {
    int growB = wRow0 + rt * 16 + quad * 4;
#pragma unroll
    for (int r = 0; r < 4; r++) {
      int grow = growB + r;
      float v0 = acc[rt][0][r], v1 = acc[rt][1][r];
      float v2 = acc[rt][2][r], v3 = acc[rt][3][r];
      if (DIAG) {
        int c0 = colT + cl;
        if (c0 == grow) v0 = NEG_BIG;
        if (c0 + 16 == grow) v1 = NEG_BIG;
        if (c0 + 32 == grow) v2 = NEG_BIG;
        if (c0 + 48 == grow) v3 = NEG_BIG;
      }
      int slot = rt * 4 + r;
      // e = exp2(v*kk - kk)  (fixed softmax max at sim=1; sims bounded by 1)
      float e0 = __builtin_exp2f(__builtin_fmaf(v0, kk, -kk));
      float e1 = __builtin_exp2f(__builtin_fmaf(v1, kk, -kk));
      float e2 = __builtin_exp2f(__builtin_fmaf(v2, kk, -kk));
      float e3 = __builtin_exp2f(__builtin_fmaf(v3, kk, -kk));
      L[slot] += (e0 + e1) + (e2 + e3);
      // argmax over the 4 candidates (first-occurrence-wins tie semantics)
      float m01 = fmaxf(v0, v1);
      int i01 = (v1 > v0) ? 1 : 0;
      float m23 = fmaxf(v2, v3);
      int i23 = (v3 > v2) ? 3 : 2;
      float mm = fmaxf(m01, m23);
      int ii = (m23 > m01) ? i23 : i01;
      if (mm > BV[slot]) {
        BV[slot] = mm;
        BI[slot] = t * 4 + ii;  // 6-bit local index: tile(4b) x nt(2b)
      }
    }
  }
}

// ------------- main fused S-pass + last-block reduction -------------
// grid = 64 rowTiles x 8 colSplits = 512 blocks, 256 threads (4 waves x 32 rows)
// Staging is VALU ds_write_b128 (R1-measured 70.7us): 8 global_load_dwordx4 all
// in flight, then 8 ds_writes. The global_load_lds DMA variant (R4) serialized
// (M0 rewrite per instr) and stalled everything: 230us. Do not switch back.
// launch_bounds(256,2): budget 256 >= ~140 demand. (256,3)/(256,4) SPILLED
// (0.6-2.2 GB scratch HBM traffic, 3-6x slowdown). Do not tighten.
__global__ __launch_bounds__(256, 2) void k_main(const __half* __restrict__ zn,
                                                 const float* __restrict__ logT,
                                                 float* __restrict__ pL,
                                                 float* __restrict__ pV,
                                                 int* __restrict__ pI,
                                                 const float* __restrict__ tsim,
                                                 int* __restrict__ cnt,
                                                 float* __restrict__ out) {
  __shared__ uint4 lds[BN * 32];  // 64 rows x 32 x 16B = 32 KB, xor-swizzled
  __shared__ int sLast;

  int bx = blockIdx.x;
  int rowTile = bx >> 3;
  int colq = bx & 7;
  int rowBase = rowTile * BM;
  int colBase = colq * CPB;
  int tid = threadIdx.x;
  int w = tid >> 6;
  int lane = tid & 63;
  int quad = lane >> 4;
  int cl = lane & 15;

  float invT = expf(-logT[0]);
  float kk = invT * LOG2E;

  // A fragments in registers: wave owns rows [rowBase+w*32, +32)
  half8 a[2][8];
  int wRow0 = rowBase + w * 32;
  {
    int ar0 = wRow0 + cl;
#pragma unroll
    for (int ks = 0; ks < 8; ks++) {
      a[0][ks] = *(const half8*)(zn + (size_t)ar0 * DIM + ks * 32 + quad * 8);
      a[1][ks] = *(const half8*)(zn + (size_t)(ar0 + 16) * DIM + ks * 32 + quad * 8);
    }
  }

  float L[8], BV[8];
  int BI[8];
#pragma unroll
  for (int s = 0; s < 8; s++) {
    L[s] = 0.f;
    BV[s] = -3e38f;
    BI[s] = 0;
  }

  for (int t = 0; t < NTILES; t++) {
    int colT = colBase + t * BN;
    __syncthreads();
    // stage B tile: 64 rows x 512 B; xor-swizzle chunk index to break bank conflicts
#pragma unroll
    for (int i = 0; i < 8; i++) {
      int idx = tid + i * 256;
      int c = idx >> 5, ch = idx & 31;
      uint4 v = *(const uint4*)(zn + (size_t)(colT + c) * DIM + ch * 8);
      lds[c * 32 + (ch ^ (c & 7))] = v;
    }
    __syncthreads();

    floatx4 acc[2][4];
#pragma unroll
    for (int rt = 0; rt < 2; rt++)
#pragma unroll
      for (int nt = 0; nt < 4; nt++) acc[rt][nt] = (floatx4){0.f, 0.f, 0.f, 0.f};

#pragma unroll
    for (int nt = 0; nt < 4; nt++) {
      int bc = nt * 16 + cl;
#pragma unroll
      for (int ks = 0; ks < 8; ks++) {
        int ch = ks * 4 + quad;
        half8 b = *(const half8*)&lds[bc * 32 + (ch ^ (bc & 7))];
        acc[0][nt] = __builtin_amdgcn_mfma_f32_16x16x32_f16(a[0][ks], b, acc[0][nt], 0, 0, 0);
        acc[1][nt] = __builtin_amdgcn_mfma_f32_16x16x32_f16(a[1][ks], b, acc[1][nt], 0, 0, 0);
      }
    }

    // diagonal can only appear when this 64-col tile overlaps the wave's 32 rows
    bool hasDiag = (colT <= wRow0 + 31) && (colT + BN - 1 >= wRow0);
    if (hasDiag)
      upd<true>(acc, t, colT, cl, quad, wRow0, kk, L, BV, BI);
    else
      upd<false>(acc, t, colT, cl, quad, wRow0, kk, L, BV, BI);
  }

  // combine the 16 per-lane partials within each quad (plain sum for L; max+idx for argmax)
#pragma unroll
  for (int s = 0; s < 8; s++) {
    float l = L[s];
    float bv = BV[s];
    int bi6 = BI[s];
    int idx = ((bi6 >> 2) << 6) + ((bi6 & 3) << 4) + cl;  // col within this colsplit
#pragma unroll
    for (int sh = 1; sh < 16; sh <<= 1) {
      l += __shfl_xor(l, sh);
      float ov = __shfl_xor(bv, sh);
      int oi = __shfl_xor(idx, sh);
      if (ov > bv || (ov == bv && oi < idx)) {
        bv = ov;
        idx = oi;
      }
    }
    L[s] = l;
    BV[s] = bv;
    BI[s] = colBase + idx;
  }

  if (cl == 0) {
#pragma unroll
    for (int rt = 0; rt < 2; rt++)
#pragma unroll
      for (int r = 0; r < 4; r++) {
        int grow = wRow0 + rt * 16 + quad * 4 + r;
        int s = rt * 4 + r;
        int p = grow * COLSPLIT + colq;
        pL[p] = L[s];
        pV[p] = BV[s];
        pI[p] = BI[s];
      }
  }

  // ---- split-K style completion: last col-split block of this rowTile reduces ----
  __threadfence();  // release partial writes to device scope
  __syncthreads();
  if (tid == 0) {
    int old = atomicAdd(&cnt[rowTile], 1);
    sLast = (old == COLSPLIT - 1) ? 1 : 0;
  }
  __syncthreads();
  if (!sLast) return;
  __threadfence();  // acquire: see other blocks' partials

  float loss = 0.f, corr = 0.f;
  if (tid < BM) {
    int row = rowBase + tid;
    float Lt = 0.f;
    float bv = -3e38f;
    int bi = -1;
#pragma unroll
    for (int q = 0; q < COLSPLIT; q++) {
      Lt += pL[row * COLSPLIT + q];
      float v = pV[row * COLSPLIT + q];
      if (v > bv) {  // ascending q => first occurrence wins
        bv = v;
        bi = pI[row * COLSPLIT + q];
      }
    }
    int tgt = (row < NHALF) ? row + NHALF : row - NHALF;
    // logZ = invT + log(Lt) (fixed max at sim=1); loss_row = logZ - tsim*invT
    loss = invT + logf(Lt) - tsim[row] * invT;
    corr = (bi == tgt) ? 1.f : 0.f;
  }
  float* sl = (float*)lds;        // reuse LDS (safe after syncthreads)
  float* sc = (float*)lds + 256;
  sl[tid] = loss;
  sc[tid] = corr;
  __syncthreads();
  for (int s = 128; s > 0; s >>= 1) {
    if (tid < s) {
      sl[tid] += sl[tid + s];
      sc[tid] += sc[tid + s];
    }
    __syncthreads();
  }
  if (tid == 0) {
    atomicAdd(out + 0, sl[0] * (1.0f / (float)NTOT));
    atomicAdd(out + 1, sc[0] * 0.5f);
  }
}

extern "C" void kernel_launch(void* const* d_in, const int* in_sizes, int n_in,
                              void* d_out, int out_size, void* d_ws, size_t ws_size,
                              hipStream_t stream) {
  const float* z1 = (const float*)d_in[0];
  const float* z2 = (const float*)d_in[1];
  const float* logT = (const float*)d_in[2];
  float* out = (float*)d_out;

  char* ws = (char*)d_ws;
  __half* zn = (__half*)ws;                                 // 4 MB
  float* tsim = (float*)(ws + 4 * 1024 * 1024);             // 32 KB
  float* pL = (float*)(ws + 4 * 1024 * 1024 + 32 * 1024);   // 256 KB
  float* pV = (float*)((char*)pL + NTOT * COLSPLIT * 4);    // 256 KB
  int* pI = (int*)((char*)pV + NTOT * COLSPLIT * 4);        // 256 KB
  int* cnt = (int*)((char*)pI + NTOT * COLSPLIT * 4);       // 256 B

  k_prep<<<NHALF / 2, 256, 0, stream>>>(z1, z2, zn, tsim, cnt, out);
  k_main<<<NROWTILE * COLSPLIT, 256, 0, stream>>>(zn, logT, pL, pV, pI, tsim, cnt, out);
}

// Round 6
// 181.211 us; speedup vs baseline: 2.7760x; 1.0144x over previous
//
#include <hip/hip_runtime.h>
#include <hip/hip_fp16.h>

#define NTOT 8192
#define NHALF 4096
#define DIM 256
#define LOG2E 1.4426950408889634f
#define NEG_BIG -1e30f
#define COLSPLIT 8
#define BM 128
#define BN 64
#define CPB (NTOT / COLSPLIT) /* 1024 cols per block */
#define NTILES (CPB / BN)     /* 16 */
#define NROWTILE (NTOT / BM)  /* 64 */

typedef _Float16 half8 __attribute__((ext_vector_type(8)));
typedef float floatx4 __attribute__((ext_vector_type(4)));

// ------------- fused prep: normalize z1|z2 -> fp16 zn, target sims, zero out -------------
__global__ __launch_bounds__(256) void k_prep(const float* __restrict__ z1,
                                              const float* __restrict__ z2,
                                              __half* __restrict__ zn,
                                              float* __restrict__ tsim,
                                              float* __restrict__ out) {
  __shared__ float sh[4][256];
  int w = threadIdx.x >> 6, lane = threadIdx.x & 63;
  int p = blockIdx.x * 2 + (w >> 1);
  int isZ2 = w & 1;
  const float* src = (isZ2 ? z2 : z1) + (size_t)p * DIM;
  float4 v = ((const float4*)src)[lane];
  float ss = v.x * v.x + v.y * v.y + v.z * v.z + v.w * v.w;
#pragma unroll
  for (int m = 1; m < 64; m <<= 1) ss += __shfl_xor(ss, m);
  float inv = 1.0f / fmaxf(sqrtf(ss), 1e-8f);
  __half h0 = __float2half_rn(v.x * inv), h1 = __float2half_rn(v.y * inv);
  __half h2 = __float2half_rn(v.z * inv), h3 = __float2half_rn(v.w * inv);
  int row = p + isZ2 * NHALF;
  __half2 a2, b2;
  a2.x = h0; a2.y = h1; b2.x = h2; b2.y = h3;
  __half2* dst = (__half2*)(zn + (size_t)row * DIM + lane * 4);
  dst[0] = a2;
  dst[1] = b2;
  float* s = sh[w];
  s[lane * 4 + 0] = __half2float(h0);
  s[lane * 4 + 1] = __half2float(h1);
  s[lane * 4 + 2] = __half2float(h2);
  s[lane * 4 + 3] = __half2float(h3);
  __syncthreads();
  if (w < 2) {  // wave w computes tsim for pair blockIdx*2 + w (fp16-rounded dot, fp32 acc)
    const float* sa = sh[w * 2];
    const float* sb = sh[w * 2 + 1];
    float4 xa = ((const float4*)sa)[lane];
    float4 xb = ((const float4*)sb)[lane];
    float d = xa.x * xb.x + xa.y * xb.y + xa.z * xb.z + xa.w * xb.w;
#pragma unroll
    for (int m = 1; m < 64; m <<= 1) d += __shfl_xor(d, m);
    if (lane == 0) {
      int pp = blockIdx.x * 2 + w;
      tsim[pp] = d;
      tsim[pp + NHALF] = d;
    }
  }
  if (blockIdx.x == 0 && threadIdx.x < 2) out[threadIdx.x] = 0.0f;
}

// ------------- per-tile epilogue: bounded-max exp-sum + argmax -------------
template <bool DIAG>
__device__ __forceinline__ void upd(const floatx4 (&acc)[2][4], int t, int colT, int cl,
                                    int quad, int wRow0, float kk, float* L, float* BV,
                                    int* BI) {
#pragma unroll
  for (int rt = 0; rt < 2; rt++) {
    int growB = wRow0 + rt * 16 + quad * 4;
#pragma unroll
    for (int r = 0; r < 4; r++) {
      int grow = growB + r;
      float v0 = acc[rt][0][r], v1 = acc[rt][1][r];
      float v2 = acc[rt][2][r], v3 = acc[rt][3][r];
      if (DIAG) {
        int c0 = colT + cl;
        if (c0 == grow) v0 = NEG_BIG;
        if (c0 + 16 == grow) v1 = NEG_BIG;
        if (c0 + 32 == grow) v2 = NEG_BIG;
        if (c0 + 48 == grow) v3 = NEG_BIG;
      }
      int slot = rt * 4 + r;
      // e = exp2(v*kk - kk)  (fixed softmax max at sim=1; sims bounded by 1)
      float e0 = __builtin_exp2f(__builtin_fmaf(v0, kk, -kk));
      float e1 = __builtin_exp2f(__builtin_fmaf(v1, kk, -kk));
      float e2 = __builtin_exp2f(__builtin_fmaf(v2, kk, -kk));
      float e3 = __builtin_exp2f(__builtin_fmaf(v3, kk, -kk));
      L[slot] += (e0 + e1) + (e2 + e3);
      // argmax over the 4 candidates (first-occurrence-wins tie semantics)
      float m01 = fmaxf(v0, v1);
      int i01 = (v1 > v0) ? 1 : 0;
      float m23 = fmaxf(v2, v3);
      int i23 = (v3 > v2) ? 3 : 2;
      float mm = fmaxf(m01, m23);
      int ii = (m23 > m01) ? i23 : i01;
      if (mm > BV[slot]) {
        BV[slot] = mm;
        BI[slot] = t * 4 + ii;  // 6-bit local index: tile(4b) x nt(2b)
      }
    }
  }
}

// ------------- main fused S-pass -------------
// grid = 64 rowTiles x 8 colSplits = 512 blocks, 256 threads (4 waves x 32 rows)
// MEASURED CONSTRAINTS (do not regress):
// - VALU ds_write_b128 staging, NOT global_load_lds DMA (DMA serialized: 230us, R4)
// - launch_bounds(256,2): (256,3)/(256,4) spill 0.6-2.2GB scratch (R2/R3)
// - NO device-scope __threadfence()/fused-reduce in this kernel: 512 agent-scope
//   fences cost ~68us of L2-writeback serialization (R5). Separate k_reduce.
// NEW (R6): register prefetch pipeline — tile t+1's 8 global_load_dwordx4 issue
// right after tile t's ds_writes, draining L2 latency under MFMA+epilogue.
__global__ __launch_bounds__(256, 2) void k_main(const __half* __restrict__ zn,
                                                 const float* __restrict__ logT,
                                                 float* __restrict__ pL,
                                                 float* __restrict__ pV,
                                                 int* __restrict__ pI) {
  __shared__ uint4 lds[BN * 32];  // 64 rows x 32 x 16B = 32 KB, xor-swizzled

  int bx = blockIdx.x;
  int rowTile = bx >> 3;
  int colq = bx & 7;
  int rowBase = rowTile * BM;
  int colBase = colq * CPB;
  int tid = threadIdx.x;
  int w = tid >> 6;
  int lane = tid & 63;
  int quad = lane >> 4;
  int cl = lane & 15;

  float invT = expf(-logT[0]);
  float kk = invT * LOG2E;

  // A fragments in registers: wave owns rows [rowBase+w*32, +32)
  half8 a[2][8];
  int wRow0 = rowBase + w * 32;
  {
    int ar0 = wRow0 + cl;
#pragma unroll
    for (int ks = 0; ks < 8; ks++) {
      a[0][ks] = *(const half8*)(zn + (size_t)ar0 * DIM + ks * 32 + quad * 8);
      a[1][ks] = *(const half8*)(zn + (size_t)(ar0 + 16) * DIM + ks * 32 + quad * 8);
    }
  }

  float L[8], BV[8];
  int BI[8];
#pragma unroll
  for (int s = 0; s < 8; s++) {
    L[s] = 0.f;
    BV[s] = -3e38f;
    BI[s] = 0;
  }

  // per-lane staging geometry (fixed across tiles)
  int sc_[8], sch_[8], sldst_[8];
#pragma unroll
  for (int i = 0; i < 8; i++) {
    int idx = tid + i * 256;
    sc_[i] = idx >> 5;
    sch_[i] = idx & 31;
    sldst_[i] = sc_[i] * 32 + (sch_[i] ^ (sc_[i] & 7));
  }

  // prefetch tile 0
  uint4 pf[8];
#pragma unroll
  for (int i = 0; i < 8; i++)
    pf[i] = *(const uint4*)(zn + (size_t)(colBase + sc_[i]) * DIM + sch_[i] * 8);

#pragma unroll
  for (int t = 0; t < NTILES; t++) {
    int colT = colBase + t * BN;
    __syncthreads();  // previous tile's LDS consumers done
#pragma unroll
    for (int i = 0; i < 8; i++) lds[sldst_[i]] = pf[i];
    // issue next tile's loads now; they stay in flight through MFMA+epilogue
    if (t + 1 < NTILES) {
#pragma unroll
      for (int i = 0; i < 8; i++)
        pf[i] = *(const uint4*)(zn + (size_t)(colT + BN + sc_[i]) * DIM + sch_[i] * 8);
    }
    __syncthreads();

    floatx4 acc[2][4];
#pragma unroll
    for (int rt = 0; rt < 2; rt++)
#pragma unroll
      for (int nt = 0; nt < 4; nt++) acc[rt][nt] = (floatx4){0.f, 0.f, 0.f, 0.f};

#pragma unroll
    for (int nt = 0; nt < 4; nt++) {
      int bc = nt * 16 + cl;
#pragma unroll
      for (int ks = 0; ks < 8; ks++) {
        int ch = ks * 4 + quad;
        half8 b = *(const half8*)&lds[bc * 32 + (ch ^ (bc & 7))];
        acc[0][nt] = __builtin_amdgcn_mfma_f32_16x16x32_f16(a[0][ks], b, acc[0][nt], 0, 0, 0);
        acc[1][nt] = __builtin_amdgcn_mfma_f32_16x16x32_f16(a[1][ks], b, acc[1][nt], 0, 0, 0);
      }
    }

    // diagonal can only appear when this 64-col tile overlaps the wave's 32 rows
    bool hasDiag = (colT <= wRow0 + 31) && (colT + BN - 1 >= wRow0);
    if (hasDiag)
      upd<true>(acc, t, colT, cl, quad, wRow0, kk, L, BV, BI);
    else
      upd<false>(acc, t, colT, cl, quad, wRow0, kk, L, BV, BI);
  }

  // combine the 16 per-lane partials within each quad (plain sum for L; max+idx for argmax)
#pragma unroll
  for (int s = 0; s < 8; s++) {
    float l = L[s];
    float bv = BV[s];
    int bi6 = BI[s];
    int idx = ((bi6 >> 2) << 6) + ((bi6 & 3) << 4) + cl;  // col within this colsplit
#pragma unroll
    for (int sh = 1; sh < 16; sh <<= 1) {
      l += __shfl_xor(l, sh);
      float ov = __shfl_xor(bv, sh);
      int oi = __shfl_xor(idx, sh);
      if (ov > bv || (ov == bv && oi < idx)) {
        bv = ov;
        idx = oi;
      }
    }
    L[s] = l;
    BV[s] = bv;
    BI[s] = colBase + idx;
  }

  if (cl == 0) {
#pragma unroll
    for (int rt = 0; rt < 2; rt++)
#pragma unroll
      for (int r = 0; r < 4; r++) {
        int grow = wRow0 + rt * 16 + quad * 4 + r;
        int s = rt * 4 + r;
        int p = grow * COLSPLIT + colq;
        pL[p] = L[s];
        pV[p] = BV[s];
        pI[p] = BI[s];
      }
  }
}

// ------------- final reduce: combine col-splits, loss + correct -------------
__global__ __launch_bounds__(256) void k_reduce(const float* __restrict__ pL,
                                                const float* __restrict__ pV,
                                                const int* __restrict__ pI,
                                                const float* __restrict__ tsim,
                                                const float* __restrict__ logT,
                                                float* __restrict__ out) {
  int row = blockIdx.x * 256 + threadIdx.x;  // grid 32 -> 8192 rows
  float invT = expf(-logT[0]);
  float Lt = 0.f;
  float bv = -3e38f;
  int bi = -1;
#pragma unroll
  for (int q = 0; q < COLSPLIT; q++) {
    Lt += pL[row * COLSPLIT + q];
    float v = pV[row * COLSPLIT + q];
    if (v > bv) {  // ascending q => first occurrence wins
      bv = v;
      bi = pI[row * COLSPLIT + q];
    }
  }
  int tgt = (row < NHALF) ? row + NHALF : row - NHALF;
  // logZ = invT + log(Lt) (fixed max at sim=1); loss_row = logZ - tsim*invT
  float loss = invT + logf(Lt) - tsim[row] * invT;
  float corr = (bi == tgt) ? 1.f : 0.f;

  __shared__ float sl[256], sc[256];
  sl[threadIdx.x] = loss;
  sc[threadIdx.x] = corr;
  __syncthreads();
  for (int s = 128; s > 0; s >>= 1) {
    if (threadIdx.x < s) {
      sl[threadIdx.x] += sl[threadIdx.x + s];
      sc[threadIdx.x] += sc[threadIdx.x + s];
    }
    __syncthreads();
  }
  if (threadIdx.x == 0) {
    atomicAdd(out + 0, sl[0] * (1.0f / (float)NTOT));
    atomicAdd(out + 1, sc[0] * 0.5f);
  }
}

extern "C" void kernel_launch(void* const* d_in, const int* in_sizes, int n_in,
                              void* d_out, int out_size, void* d_ws, size_t ws_size,
                              hipStream_t stream) {
  const float* z1 = (const float*)d_in[0];
  const float* z2 = (const float*)d_in[1];
  const float* logT = (const float*)d_in[2];
  float* out = (float*)d_out;

  char* ws = (char*)d_ws;
  __half* zn = (__half*)ws;                                 // 4 MB
  float* tsim = (float*)(ws + 4 * 1024 * 1024);             // 32 KB
  float* pL = (float*)(ws + 4 * 1024 * 1024 + 32 * 1024);   // 256 KB
  float* pV = (float*)((char*)pL + NTOT * COLSPLIT * 4);    // 256 KB
  int* pI = (int*)((char*)pV + NTOT * COLSPLIT * 4);        // 256 KB

  k_prep<<<NHALF / 2, 256, 0, stream>>>(z1, z2, zn, tsim, out);
  k_main<<<NROWTILE * COLSPLIT, 256, 0, stream>>>(zn, logT, pL, pV, pI);
  k_reduce<<<NTOT / 256, 256, 0, stream>>>(pL, pV, pI, tsim, logT, out);
}